// Round 3
// baseline (762.066 us; speedup 1.0000x reference)
//
#include <hip/hip_runtime.h>
#include <hip/hip_bf16.h>
#include <stdint.h>

#define NE    64
#define DIN   512
#define DOUT  512
#define TTOK  131072
#define BM    128
#define BN    128
#define BK    64
#define NKSTEP (DIN / BK)                 // 8
#define TILES_TOTAL (TTOK / BM + NE)      // 1088 = provable bound on ntiles
#define NXCD  8
#define TPX   (TILES_TOTAL / NXCD)        // 136 tiles per XCD

typedef __bf16 bf16x8_t __attribute__((ext_vector_type(8)));
typedef __bf16 bf16x4_t __attribute__((ext_vector_type(4)));
typedef float  f32x4_t  __attribute__((ext_vector_type(4)));

// ws layout: ws[0] = ntiles; tile table at ws+4 (int4 per tile: e, row0, row_end, pad)
__global__ void setup_tiles(const int* __restrict__ cnt, int* __restrict__ ws) {
    int e = threadIdx.x;
    if (e >= NE) return;
    int off = 0, tbase = 0;
    for (int i = 0; i < e; ++i) {
        int c = cnt[i];
        off += c;
        tbase += (c + (BM - 1)) / BM;
    }
    int c = cnt[e];
    int nt = (c + (BM - 1)) / BM;
    int* tbl = ws + 4;
    for (int t = 0; t < nt; ++t) {
        int idx = tbase + t;
        tbl[4 * idx + 0] = e;
        tbl[4 * idx + 1] = off + t * BM;
        tbl[4 * idx + 2] = off + c;
        tbl[4 * idx + 3] = 0;
    }
    if (e == NE - 1) ws[0] = tbase + nt;
}

__global__ __launch_bounds__(256, 4) void moe_gemm(
    const float* __restrict__ inp,
    const float* __restrict__ weight,
    const float* __restrict__ bias,
    const int* __restrict__ ws,
    float* __restrict__ out)
{
    // SINGLE buffer: (A,B) * 128 rows * 64 k * 2B = 32 KiB -> 4 blocks/CU
    __shared__ __align__(16) unsigned char lds[2 * BM * BK * 2];

    // XCD-aware mapping: 4 blocks sharing one A-tile -> same XCD (same L2);
    // consecutive tiles of one expert -> same XCD (weight panel stays hot).
    const int bid  = blockIdx.x;
    const int xcd  = bid & (NXCD - 1);
    const int slot = bid >> 3;                    // 0..543
    const int tile = xcd * TPX + (slot >> 2);
    const int n0   = (slot & 3) * BN;

    const int ntiles = ws[0];
    if (tile >= ntiles) return;
    const int4 ti = ((const int4*)(ws + 4))[tile];
    const int e = ti.x, row0 = ti.y, row_end = ti.z;

    const int tid  = threadIdx.x;
    const int lane = tid & 63;
    const int wave = tid >> 6;
    const int wr = (wave >> 1) * 64;   // wave row offset in tile
    const int wc = (wave & 1) * 64;    // wave col offset in tile

    // staging: thread -> (row = tid/16 + 16*i, 16B chunk = tid%16)
    const int srow = tid >> 4;
    const int sc4  = tid & 15;

    const float* __restrict__ aptr = inp + (size_t)row0 * DIN + sc4 * 4;
    const float* __restrict__ bptr = weight + (size_t)e * (DOUT * DIN)
                                     + (size_t)n0 * DIN + sc4 * 4;

    f32x4_t ra[8], rb[8];

    auto loadg = [&](int kk) {
        const int k0 = kk * BK;
#pragma unroll
        for (int i = 0; i < 8; ++i) {
            const int row = srow + i * 16;
            if (row0 + row < row_end) {
                ra[i] = *(const f32x4_t*)(aptr + (size_t)row * DIN + k0);
            } else {
                f32x4_t z = {0.f, 0.f, 0.f, 0.f};
                ra[i] = z;
            }
            rb[i] = *(const f32x4_t*)(bptr + (size_t)row * DIN + k0);
        }
    };

    // XOR-swizzled LDS addressing (T2): conflict-free ds_read_b128 on
    // 128B-stride rows (verified: SQ_LDS_BANK_CONFLICT == 0 in round 2).
    auto lds_addr = [&](int which, int row, int kbyte) -> unsigned char* {
        return &lds[which * 16384 + row * 128 + (kbyte ^ ((row & 7) << 4))];
    };

    auto store_lds = [&]() {
#pragma unroll
        for (int i = 0; i < 8; ++i) {
            const int row = srow + i * 16;
            bf16x4_t ha, hb;
#pragma unroll
            for (int j = 0; j < 4; ++j) {
                ha[j] = (__bf16)ra[i][j];
                hb[j] = (__bf16)rb[i][j];
            }
            *(bf16x4_t*)lds_addr(0, row, sc4 * 8) = ha;
            *(bf16x4_t*)lds_addr(1, row, sc4 * 8) = hb;
        }
    };

    f32x4_t acc[4][4] = {};

    const int frow = lane & 15;          // fragment row within 16
    const int fkb  = (lane >> 4) * 16;   // fragment k-byte within 32-K slice

    auto compute = [&]() {
#pragma unroll
        for (int ks = 0; ks < 2; ++ks) {
            bf16x8_t af[4], bg[4];
#pragma unroll
            for (int m = 0; m < 4; ++m)
                af[m] = *(const bf16x8_t*)lds_addr(0, wr + m * 16 + frow, ks * 64 + fkb);
#pragma unroll
            for (int n = 0; n < 4; ++n)
                bg[n] = *(const bf16x8_t*)lds_addr(1, wc + n * 16 + frow, ks * 64 + fkb);
#pragma unroll
            for (int m = 0; m < 4; ++m)
#pragma unroll
                for (int n = 0; n < 4; ++n)
                    acc[m][n] = __builtin_amdgcn_mfma_f32_16x16x32_bf16(
                        af[m], bg[n], acc[m][n], 0, 0, 0);
        }
    };

    // single-LDS-buffer loop, register-prefetch double-buffered
    loadg(0);
    store_lds();
    __syncthreads();
#pragma unroll 1
    for (int kk = 0; kk < NKSTEP; ++kk) {
        if (kk + 1 < NKSTEP) loadg(kk + 1);   // prefetch into regs (T14)
        compute();
        __syncthreads();                      // all waves done reading LDS
        if (kk + 1 < NKSTEP) {
            store_lds();
            __syncthreads();                  // next tile visible
        }
    }

    // epilogue: C/D layout col = lane&15, row = (lane>>4)*4 + j  [m89]
    // non-temporal stores: no write-allocate RFO fetch of output lines
    const int crow = (lane >> 4) * 4;
    const int ccol = lane & 15;
    float bv[4];
#pragma unroll
    for (int n = 0; n < 4; ++n)
        bv[n] = bias[e * DOUT + n0 + wc + n * 16 + ccol];
#pragma unroll
    for (int m = 0; m < 4; ++m) {
#pragma unroll
        for (int j = 0; j < 4; ++j) {
            const int grow = row0 + wr + m * 16 + crow + j;
            if (grow < row_end) {
                float* orow = out + (size_t)grow * DOUT + n0 + wc + ccol;
#pragma unroll
                for (int n = 0; n < 4; ++n)
                    __builtin_nontemporal_store(acc[m][n][j] + bv[n], orow + n * 16);
            }
        }
    }
}

extern "C" void kernel_launch(void* const* d_in, const int* in_sizes, int n_in,
                              void* d_out, int out_size, void* d_ws, size_t ws_size,
                              hipStream_t stream) {
    const float* inp    = (const float*)d_in[0];
    const float* weight = (const float*)d_in[1];
    const float* bias   = (const float*)d_in[2];
    const int* cnt      = (const int*)d_in[3];   // int64 in reference, delivered as int32
    float* out = (float*)d_out;
    int* ws = (int*)d_ws;

    hipLaunchKernelGGL(setup_tiles, dim3(1), dim3(64), 0, stream, cnt, ws);
    hipLaunchKernelGGL(moe_gemm, dim3(TILES_TOTAL * 4), dim3(256), 0, stream,
                       inp, weight, bias, ws, out);
}

// Round 4
// 222.591 us; speedup vs baseline: 3.4236x; 3.4236x over previous
//
#include <hip/hip_runtime.h>
#include <hip/hip_bf16.h>
#include <stdint.h>

#define NE    64
#define DIN   512
#define DOUT  512
#define TTOK  131072
#define BM    128
#define BN    128
#define BK    64
#define NKSTEP (DIN / BK)                 // 8
#define TILES_TOTAL (TTOK / BM + NE)      // 1088 = provable bound on ntiles
#define NXCD  8
#define TPX   (TILES_TOTAL / NXCD)        // 136 tiles per XCD

typedef __bf16 bf16x8_t __attribute__((ext_vector_type(8)));
typedef __bf16 bf16x4_t __attribute__((ext_vector_type(4)));
typedef float  f32x4_t  __attribute__((ext_vector_type(4)));

// ws layout: ws[0] = ntiles; tile table at ws+4 (int4 per tile: e, row0, row_end, pad)
__global__ void setup_tiles(const int* __restrict__ cnt, int* __restrict__ ws) {
    int e = threadIdx.x;
    if (e >= NE) return;
    int off = 0, tbase = 0;
    for (int i = 0; i < e; ++i) {
        int c = cnt[i];
        off += c;
        tbase += (c + (BM - 1)) / BM;
    }
    int c = cnt[e];
    int nt = (c + (BM - 1)) / BM;
    int* tbl = ws + 4;
    for (int t = 0; t < nt; ++t) {
        int idx = tbase + t;
        tbl[4 * idx + 0] = e;
        tbl[4 * idx + 1] = off + t * BM;
        tbl[4 * idx + 2] = off + c;
        tbl[4 * idx + 3] = 0;
    }
    if (e == NE - 1) ws[0] = tbase + nt;
}

__global__ __launch_bounds__(256, 3) void moe_gemm(
    const float* __restrict__ inp,
    const float* __restrict__ weight,
    const float* __restrict__ bias,
    const int* __restrict__ ws,
    float* __restrict__ out)
{
    // SINGLE buffer: (A,B) * 128 rows * 64 k * 2B = 32 KiB -> 3 blocks/CU (96KB)
    __shared__ __align__(16) unsigned char lds[2 * BM * BK * 2];

    // XCD-aware mapping: 4 blocks sharing one A-tile -> same XCD (same L2);
    // consecutive tiles of one expert -> same XCD (weight panel stays hot).
    const int bid  = blockIdx.x;
    const int xcd  = bid & (NXCD - 1);
    const int slot = bid >> 3;                    // 0..543
    const int tile = xcd * TPX + (slot >> 2);
    const int n0   = (slot & 3) * BN;

    const int ntiles = ws[0];
    if (tile >= ntiles) return;
    const int4 ti = ((const int4*)(ws + 4))[tile];
    const int e = ti.x, row0 = ti.y, row_end = ti.z;

    const int tid  = threadIdx.x;
    const int lane = tid & 63;
    const int wave = tid >> 6;
    const int wr = (wave >> 1) * 64;   // wave row offset in tile
    const int wc = (wave & 1) * 64;    // wave col offset in tile

    // staging: thread -> (row = tid/16 + 16*i, 16B chunk = tid%16)
    const int srow = tid >> 4;
    const int sc4  = tid & 15;

    const float* __restrict__ aptr = inp + (size_t)row0 * DIN + sc4 * 4;
    const float* __restrict__ bptr = weight + (size_t)e * (DOUT * DIN)
                                     + (size_t)n0 * DIN + sc4 * 4;

    f32x4_t ra[8], rb[8];

    auto loadg = [&](int kk) {
        const int k0 = kk * BK;
#pragma unroll
        for (int i = 0; i < 8; ++i) {
            const int row = srow + i * 16;
            if (row0 + row < row_end) {
                ra[i] = *(const f32x4_t*)(aptr + (size_t)row * DIN + k0);
            } else {
                f32x4_t z = {0.f, 0.f, 0.f, 0.f};
                ra[i] = z;
            }
            rb[i] = *(const f32x4_t*)(bptr + (size_t)row * DIN + k0);
        }
    };

    // XOR-swizzled LDS addressing (T2): conflict-free ds_read_b128 on
    // 128B-stride rows (verified: SQ_LDS_BANK_CONFLICT == 0 in rounds 2-3).
    auto lds_addr = [&](int which, int row, int kbyte) -> unsigned char* {
        return &lds[which * 16384 + row * 128 + (kbyte ^ ((row & 7) << 4))];
    };

    auto store_lds = [&]() {
#pragma unroll
        for (int i = 0; i < 8; ++i) {
            const int row = srow + i * 16;
            bf16x4_t ha, hb;
#pragma unroll
            for (int j = 0; j < 4; ++j) {
                ha[j] = (__bf16)ra[i][j];
                hb[j] = (__bf16)rb[i][j];
            }
            *(bf16x4_t*)lds_addr(0, row, sc4 * 8) = ha;
            *(bf16x4_t*)lds_addr(1, row, sc4 * 8) = hb;
        }
    };

    f32x4_t acc[4][4] = {};

    const int frow = lane & 15;          // fragment row within 16
    const int fkb  = (lane >> 4) * 16;   // fragment k-byte within 32-K slice

    auto compute = [&]() {
#pragma unroll
        for (int ks = 0; ks < 2; ++ks) {
            bf16x8_t af[4], bg[4];
#pragma unroll
            for (int m = 0; m < 4; ++m)
                af[m] = *(const bf16x8_t*)lds_addr(0, wr + m * 16 + frow, ks * 64 + fkb);
#pragma unroll
            for (int n = 0; n < 4; ++n)
                bg[n] = *(const bf16x8_t*)lds_addr(1, wc + n * 16 + frow, ks * 64 + fkb);
#pragma unroll
            for (int m = 0; m < 4; ++m)
#pragma unroll
                for (int n = 0; n < 4; ++n)
                    acc[m][n] = __builtin_amdgcn_mfma_f32_16x16x32_bf16(
                        af[m], bg[n], acc[m][n], 0, 0, 0);
        }
    };

    // single-LDS-buffer loop, register-prefetch double-buffered.
    // Last iteration peeled so loadg is UNCONDITIONAL in-loop; sched_barrier(0)
    // pins the global loads before compute (round 3: compiler sank them under
    // launch_bounds(256,4), killing the prefetch — VGPR_Count=64 was the tell).
    loadg(0);
    store_lds();
    __syncthreads();
#pragma unroll 1
    for (int kk = 0; kk < NKSTEP - 1; ++kk) {
        loadg(kk + 1);                        // prefetch into regs (T14)
        __builtin_amdgcn_sched_barrier(0);    // loads must issue before compute
        compute();
        __syncthreads();                      // all waves done reading LDS
        store_lds();
        __syncthreads();                      // next tile visible
    }
    compute();

    // epilogue: C/D layout col = lane&15, row = (lane>>4)*4 + j  [m89]
    // plain cached stores (NT scalar stores caused 6x write amplification +
    // ECC RMW fetch in round 3)
    const int crow = (lane >> 4) * 4;
    const int ccol = lane & 15;
    float bv[4];
#pragma unroll
    for (int n = 0; n < 4; ++n)
        bv[n] = bias[e * DOUT + n0 + wc + n * 16 + ccol];
#pragma unroll
    for (int m = 0; m < 4; ++m) {
#pragma unroll
        for (int j = 0; j < 4; ++j) {
            const int grow = row0 + wr + m * 16 + crow + j;
            if (grow < row_end) {
                float* orow = out + (size_t)grow * DOUT + n0 + wc + ccol;
#pragma unroll
                for (int n = 0; n < 4; ++n)
                    orow[n * 16] = acc[m][n][j] + bv[n];
            }
        }
    }
}

extern "C" void kernel_launch(void* const* d_in, const int* in_sizes, int n_in,
                              void* d_out, int out_size, void* d_ws, size_t ws_size,
                              hipStream_t stream) {
    const float* inp    = (const float*)d_in[0];
    const float* weight = (const float*)d_in[1];
    const float* bias   = (const float*)d_in[2];
    const int* cnt      = (const int*)d_in[3];   // int64 in reference, delivered as int32
    float* out = (float*)d_out;
    int* ws = (int*)d_ws;

    hipLaunchKernelGGL(setup_tiles, dim3(1), dim3(64), 0, stream, cnt, ws);
    hipLaunchKernelGGL(moe_gemm, dim3(TILES_TOTAL * 4), dim3(256), 0, stream,
                       inp, weight, bias, ws, out);
}